// Round 5
// baseline (243.371 us; speedup 1.0000x reference)
//
#include <hip/hip_runtime.h>
#include <hip/hip_bf16.h>

// MHA: H=16, DM=1024, DK=DV=64, S=2048, B=2. fp32 in/out, bf16 MFMA internals.
// ws (32MB): [0,8MB): Wt (3x2MB, dead after proj) -> reused as cc [4096][1024] bf16
//            [8,16MB): qws [hb][s][64] -> reused as WOt [n][k] after attn
//            [16,24MB): kws [hb][s][64]
//            [24,32MB): vtws [hb][d][pos] (transposed V, pos permuted per 64-block)

typedef __bf16 bf16;
typedef bf16 bf16x8 __attribute__((ext_vector_type(8)));
typedef bf16 bf16x4 __attribute__((ext_vector_type(4)));
typedef float f32x4 __attribute__((ext_vector_type(4)));

#define MFMA16(a, b, c) __builtin_amdgcn_mfma_f32_16x16x32_bf16((a), (b), (c), 0, 0, 0)

static __device__ __forceinline__ bf16x8 load8(const bf16* p) {
  return *reinterpret_cast<const bf16x8*>(p);
}
static __device__ __forceinline__ void store8(bf16* p, bf16x8 v) {
  *reinterpret_cast<bf16x8*>(p) = v;
}
static __device__ __forceinline__ void store4(bf16* p, bf16x4 v) {
  *reinterpret_cast<bf16x4*>(p) = v;
}
static __device__ __forceinline__ bf16x8 cvt8(float4 a, float4 b) {
  bf16x8 o;
  o[0] = (bf16)a.x; o[1] = (bf16)a.y; o[2] = (bf16)a.z; o[3] = (bf16)a.w;
  o[4] = (bf16)b.x; o[5] = (bf16)b.y; o[6] = (bf16)b.z; o[7] = (bf16)b.w;
  return o;
}
static __device__ __forceinline__ f32x4 zero4() {
  f32x4 v; v[0] = 0.f; v[1] = 0.f; v[2] = 0.f; v[3] = 0.f; return v;
}
// async global->LDS, 16B per lane; lds base wave-uniform (HW scatters lane*16)
static __device__ __forceinline__ void gload_lds16(const bf16* g, bf16* l) {
  __builtin_amdgcn_global_load_lds(
      (const __attribute__((address_space(1))) void*)g,
      (__attribute__((address_space(3))) void*)l, 16, 0, 0);
}

// ---------------------------------------------------------------------------
// K0a: merged W transpose+convert. z: 0..47 -> (tensor=z/16, head=z%16).
// in[h][1024][64] -> Wt[z*64 + d][m].  WQ scaled by 0.125*log2(e) (exp2 softmax).
// ---------------------------------------------------------------------------
__global__ __launch_bounds__(256) void wcvt_kernel(const float* __restrict__ WQ,
                                                   const float* __restrict__ WK,
                                                   const float* __restrict__ WV,
                                                   bf16* __restrict__ out) {
  __shared__ float tile[32][33];
  const int zz = blockIdx.z;
  const int tau = zz >> 4;
  const float* in = ((tau == 0) ? WQ : (tau == 1) ? WK : WV) + (size_t)(zz & 15) * 65536;
  bf16* o = out + (size_t)zz * 65536;
  const float scale = (tau == 0) ? 0.125f * 1.44269504f : 1.0f;
  const int r0 = blockIdx.y * 32, c0 = blockIdx.x * 32;
  const int tx = threadIdx.x & 31, ty = threadIdx.x >> 5;
#pragma unroll
  for (int i = 0; i < 32; i += 8) tile[ty + i][tx] = in[(size_t)(r0 + ty + i) * 64 + c0 + tx];
  __syncthreads();
#pragma unroll
  for (int i = 0; i < 32; i += 8)
    o[(size_t)(c0 + ty + i) * 1024 + r0 + tx] = (bf16)(tile[tx][ty + i] * scale);
}

// ---------------------------------------------------------------------------
// K0b: generic transpose+convert (for WO 1024x1024).
// ---------------------------------------------------------------------------
__global__ __launch_bounds__(256) void tcvt_kernel(const float* __restrict__ in,
                                                   bf16* __restrict__ out, int R, int C) {
  __shared__ float tile[32][33];
  const int r0 = blockIdx.y * 32, c0 = blockIdx.x * 32;
  const int tx = threadIdx.x & 31, ty = threadIdx.x >> 5;
#pragma unroll
  for (int i = 0; i < 32; i += 8) tile[ty + i][tx] = in[(size_t)(r0 + ty + i) * C + c0 + tx];
  __syncthreads();
#pragma unroll
  for (int i = 0; i < 32; i += 8)
    out[(size_t)(c0 + ty + i) * R + r0 + tx] = (bf16)tile[tx][ty + i];
}

// ---------------------------------------------------------------------------
// K1: QKV projection, software-pipelined (LDS dbuf, 1 barrier/step).
// Linear grid 768: id = n*96 + w (w = z*32+m) so the 8 n-blocks sharing an
// X panel have id = w (mod 8) -> same XCD -> X fetched once per panel.
// ---------------------------------------------------------------------------
__global__ __launch_bounds__(256) void proj_kernel(
    const float* __restrict__ X0, const float* __restrict__ X1, const float* __restrict__ X2,
    const bf16* __restrict__ Wt, bf16* __restrict__ qws, bf16* __restrict__ kws,
    bf16* __restrict__ vtws) {
  const int id = blockIdx.x;
  const int n = id / 96;
  const int w = id % 96;
  const int z = w >> 5;
  const int m = w & 31;
  const float* X = (z == 0) ? X0 : ((z == 1) ? X1 : X2);
  const bf16* Wz = Wt + (size_t)z * 1024 * 1024;
  const int mBase = m * 128;
  const int nBase = n * 128;

  __shared__ bf16 Al[2][128][40];   // padded: conflict-free frag reads
  __shared__ bf16 Bl[2][128 * 32];  // swizzled async

  const int t = threadIdx.x;
  const int lane = t & 63;
  const int wave = t >> 6;
  const int wm = (wave >> 1) * 64;
  const int wn = (wave & 1) * 64;
  const int ln = lane & 15;
  const int quad = lane >> 4;
  const int bswz = quad ^ ((ln >> 1) & 3);

  f32x4 acc[4][4];
#pragma unroll
  for (int i = 0; i < 4; i++)
#pragma unroll
    for (int j = 0; j < 4; j++) acc[i][j] = zero4();

  const int ar = t >> 1;
  const int ak = (t & 1) * 16;
  const float4* Abase = reinterpret_cast<const float4*>(X + (size_t)(mBase + ar) * 1024 + ak);

  float4 pv[4];
#pragma unroll
  for (int i = 0; i < 4; i++) pv[i] = Abase[i];  // k0=0
#pragma unroll
  for (int i = 0; i < 2; i++) {  // async B tile 0
    const int c = i * 256 + t;
    const int mp = c >> 2;
    const int ql = (c & 3) ^ ((mp >> 1) & 3);
    gload_lds16(Wz + (size_t)(nBase + mp) * 1024 + ql * 8, &Bl[0][(i * 256 + wave * 64) * 8]);
  }
  store8(&Al[0][ar][ak], cvt8(pv[0], pv[1]));
  store8(&Al[0][ar][ak + 8], cvt8(pv[2], pv[3]));
  __syncthreads();

  for (int k0 = 0; k0 < 1024; k0 += 32) {
    const int cur = (k0 >> 5) & 1, nxt = cur ^ 1;
    const bool more = (k0 + 32) < 1024;
    if (more) {
      const int kn = (k0 + 32) >> 2;  // in float4 units
#pragma unroll
      for (int i = 0; i < 4; i++) pv[i] = Abase[kn + i];
#pragma unroll
      for (int i = 0; i < 2; i++) {
        const int c = i * 256 + t;
        const int mp = c >> 2;
        const int ql = (c & 3) ^ ((mp >> 1) & 3);
        gload_lds16(Wz + (size_t)(nBase + mp) * 1024 + k0 + 32 + ql * 8,
                    &Bl[nxt][(i * 256 + wave * 64) * 8]);
      }
    }
    bf16x8 a[4], bfr[4];
#pragma unroll
    for (int i = 0; i < 4; i++) a[i] = load8(&Al[cur][wm + i * 16 + ln][quad * 8]);
#pragma unroll
    for (int j = 0; j < 4; j++) bfr[j] = load8(&Bl[cur][((wn + j * 16 + ln) * 4 + bswz) * 8]);
#pragma unroll
    for (int i = 0; i < 4; i++)
#pragma unroll
      for (int j = 0; j < 4; j++) acc[i][j] = MFMA16(a[i], bfr[j], acc[i][j]);
    if (more) {
      store8(&Al[nxt][ar][ak], cvt8(pv[0], pv[1]));
      store8(&Al[nxt][ar][ak + 8], cvt8(pv[2], pv[3]));
    }
    __syncthreads();
  }

  // Epilogue: C/D row=quad*4+r, col=ln
#pragma unroll
  for (int i = 0; i < 4; i++) {
#pragma unroll
    for (int j = 0; j < 4; j++) {
      const int col = nBase + wn + j * 16 + ln;
      const int h = col >> 6, d = col & 63;
#pragma unroll
      for (int r = 0; r < 4; r++) {
        const int row = mBase + wm + i * 16 + quad * 4 + r;  // row = s*2+b
        const int s = row >> 1, bb = row & 1;
        const int hb = h * 2 + bb;
        const bf16 val = (bf16)acc[i][j][r];
        if (z == 0) {
          qws[((size_t)hb * 2048 + s) * 64 + d] = val;
        } else if (z == 1) {
          kws[((size_t)hb * 2048 + s) * 64 + d] = val;
        } else {
          // 64-granular permuted pos: kv=s&63 -> p = (kv&15)*4 + (kv>>4)
          const int pos = (s & ~63) | ((s & 15) << 2) | ((s >> 4) & 3);
          vtws[((size_t)hb * 64 + d) * 2048 + pos] = val;
        }
      }
    }
  }
}

// ---------------------------------------------------------------------------
// K2: causal flash attention.  Grid 512 = hb(32) x qb(16), descending work
// (qb = 15 - id>>5 -> 32-tile blocks dispatch first).  Block = 128 q-rows,
// 4 waves x 32 rows, KV tile 64.
//   K: LDS double-buffer, async global_load_lds, 1 barrier/tile.
//   V: B-frags straight from global (L2-resident, wave-invariant -> no LDS).
//   P: per-wave padded LDS (stride 72 -> all accesses <=2-way, free).
// LDS total 34KB -> up to 4 blocks/CU (vs R4's 96KB -> 1/CU, the 9%-MfmaUtil
// culprit).  Softmax in exp2 domain (log2e folded into WQ).
// ---------------------------------------------------------------------------
__global__ __launch_bounds__(256, 3) void attn_kernel(
    const bf16* __restrict__ qws, const bf16* __restrict__ kws, const bf16* __restrict__ vtws,
    bf16* __restrict__ cc) {
  const int id = blockIdx.x;
  const int hb = id & 31;          // same hb -> same XCD (id%8 preserved)
  const int qb = 15 - (id >> 5);   // big blocks first
  const int q0 = qb * 128;
  const int h = hb >> 1, b = hb & 1;

  const int t = threadIdx.x;
  const int lane = t & 63;
  const int wave = t >> 6;
  const int ln = lane & 15;
  const int quad = lane >> 4;
  const int swz3 = ln & 7;

  const bf16* qh = qws + (size_t)hb * 2048 * 64;
  const bf16* kh = kws + (size_t)hb * 2048 * 64;
  const bf16* vh = vtws + (size_t)hb * 64 * 2048;

  __shared__ bf16 Kl[2][64 * 64];  // swizzled [kv][64], dbuf (16KB)
  __shared__ bf16 Pl[4][32 * 72];  // per-wave P, padded stride 72 (18KB)
  bf16* Plw = &Pl[wave][0];

  bf16x8 ones;
#pragma unroll
  for (int i = 0; i < 8; i++) ones[i] = (bf16)1.0f;

  // Q A-frags: rows q0+wave*32+mb*16+ln, k = hh*32+quad*8+j
  bf16x8 qf[2][2];
#pragma unroll
  for (int mb = 0; mb < 2; mb++)
#pragma unroll
    for (int hh = 0; hh < 2; hh++)
      qf[mb][hh] = load8(qh + (size_t)(q0 + wave * 32 + mb * 16 + ln) * 64 + hh * 32 + quad * 8);

  f32x4 accO[2][4];
  f32x4 accL[2];
#pragma unroll
  for (int mb = 0; mb < 2; mb++) {
    accL[mb] = zero4();
#pragma unroll
    for (int d = 0; d < 4; d++) accO[mb][d] = zero4();
  }

  // prologue: stage K tile 0 (64 rows x 64 = 512 16B chunks, xor-swizzled)
#pragma unroll
  for (int i = 0; i < 2; i++) {
    const int c = i * 256 + t;
    const int mp = c >> 3;
    const int ql = (c & 7) ^ (mp & 7);
    gload_lds16(kh + (size_t)mp * 64 + ql * 8, &Kl[0][(i * 256 + wave * 64) * 8]);
  }

  const int Jmax = 2 * qb + 2;
  for (int jt = 0; jt < Jmax; jt++) {
    const int kt0 = jt * 64;
    const int cur = jt & 1, nxt = cur ^ 1;
    __syncthreads();  // drains tile-jt async loads (issued a full tile ago)
    if (jt + 1 < Jmax) {
      const int nt0 = kt0 + 64;
#pragma unroll
      for (int i = 0; i < 2; i++) {
        const int c = i * 256 + t;
        const int mp = c >> 3;
        const int ql = (c & 7) ^ (mp & 7);
        gload_lds16(kh + (size_t)(nt0 + mp) * 64 + ql * 8, &Kl[nxt][(i * 256 + wave * 64) * 8]);
      }
    }

    // S = Q K^T  (log2e*scale folded into Q)
    f32x4 sv[2][4];
#pragma unroll
    for (int nt = 0; nt < 4; nt++) {
      const int mm = nt * 16 + ln;
      bf16x8 b0 = load8(&Kl[cur][(mm * 8 + (quad ^ swz3)) * 8]);
      bf16x8 b1 = load8(&Kl[cur][(mm * 8 + ((quad + 4) ^ swz3)) * 8]);
#pragma unroll
      for (int mb = 0; mb < 2; mb++) {
        f32x4 s = MFMA16(qf[mb][0], b0, zero4());
        s = MFMA16(qf[mb][1], b1, s);
        sv[mb][nt] = s;
      }
    }

    // V B-frags from global (L2): row d*16+ln, 16B at pos kt0+(ks*4+quad)*8
    bf16x8 vb[2][4];
#pragma unroll
    for (int ks = 0; ks < 2; ks++)
#pragma unroll
      for (int d = 0; d < 4; d++)
        vb[ks][d] = load8(vh + (size_t)(d * 16 + ln) * 2048 + kt0 + (ks * 4 + quad) * 8);

    if (jt >= 2 * qb) {  // diagonal tiles: causal mask
#pragma unroll
      for (int mb = 0; mb < 2; mb++)
#pragma unroll
        for (int nt = 0; nt < 4; nt++) {
          const int kg = kt0 + nt * 16 + ln;
#pragma unroll
          for (int r = 0; r < 4; r++) {
            const int qg = q0 + wave * 32 + mb * 16 + quad * 4 + r;
            if (kg > qg) sv[mb][nt][r] = -1e30f;
          }
        }
    }

    // P = 2^S -> per-wave padded LDS, p = ln*4+nt (b64 stores, slot=ln)
#pragma unroll
    for (int mb = 0; mb < 2; mb++) {
#pragma unroll
      for (int r = 0; r < 4; r++) {
        const int row = mb * 16 + quad * 4 + r;
        bf16x4 pw;
#pragma unroll
        for (int nt = 0; nt < 4; nt++) pw[nt] = (bf16)exp2f(sv[mb][nt][r]);
        store4(Plw + row * 72 + ln * 4, pw);
      }
    }

    // O += P V ; l += P * 1   (same-wave DS in-order: no barrier needed)
#pragma unroll
    for (int ks = 0; ks < 2; ks++) {
      bf16x8 pa[2];
#pragma unroll
      for (int mb = 0; mb < 2; mb++)
        pa[mb] = load8(Plw + (mb * 16 + ln) * 72 + (ks * 4 + quad) * 8);
#pragma unroll
      for (int d = 0; d < 4; d++)
#pragma unroll
        for (int mb = 0; mb < 2; mb++) accO[mb][d] = MFMA16(pa[mb], vb[ks][d], accO[mb][d]);
#pragma unroll
      for (int mb = 0; mb < 2; mb++) accL[mb] = MFMA16(pa[mb], ones, accL[mb]);
    }
  }

  // epilogue: O /= l, write concat [s*2+b][h*64+...]
#pragma unroll
  for (int mb = 0; mb < 2; mb++) {
#pragma unroll
    for (int r = 0; r < 4; r++) {
      const float inv = 1.0f / accL[mb][r];
      const int s = q0 + wave * 32 + mb * 16 + quad * 4 + r;
#pragma unroll
      for (int d = 0; d < 4; d++)
        cc[((size_t)s * 2 + b) * 1024 + h * 64 + d * 16 + ln] = (bf16)(accO[mb][d][r] * inv);
    }
  }
}

// ---------------------------------------------------------------------------
// K3: output projection, dbuf async both operands. Grid 512: id = n*64+m so
// the 8 n-blocks sharing a cc panel share an XCD. Tile 64m x 128n.
// ---------------------------------------------------------------------------
__global__ __launch_bounds__(256) void out_kernel(
    const bf16* __restrict__ A, const bf16* __restrict__ Bt, float* __restrict__ outp) {
  const int id = blockIdx.x;
  const int nb = id >> 6;
  const int mb = id & 63;
  const int mBase = mb * 64, nBase = nb * 128;

  __shared__ bf16 Al[2][64 * 32];
  __shared__ bf16 Bl[2][128 * 32];

  const int t = threadIdx.x;
  const int lane = t & 63;
  const int wave = t >> 6;
  const int wm = (wave >> 1) * 32;
  const int wn = (wave & 1) * 64;
  const int ln = lane & 15;
  const int quad = lane >> 4;
  const int bswz = quad ^ ((ln >> 1) & 3);

  f32x4 acc[2][4];
#pragma unroll
  for (int i = 0; i < 2; i++)
#pragma unroll
    for (int j = 0; j < 4; j++) acc[i][j] = zero4();

  const int amp = t >> 2, aql = (t & 3) ^ ((amp >> 1) & 3);

  // prologue: tile 0
  gload_lds16(A + (size_t)(mBase + amp) * 1024 + aql * 8, &Al[0][(wave * 64) * 8]);
#pragma unroll
  for (int i = 0; i < 2; i++) {
    const int c = i * 256 + t;
    const int mp = c >> 2, ql = (c & 3) ^ ((mp >> 1) & 3);
    gload_lds16(Bt + (size_t)(nBase + mp) * 1024 + ql * 8, &Bl[0][(i * 256 + wave * 64) * 8]);
  }
  __syncthreads();

  for (int k0 = 0; k0 < 1024; k0 += 32) {
    const int cur = (k0 >> 5) & 1, nxt = cur ^ 1;
    const bool more = (k0 + 32) < 1024;
    if (more) {
      gload_lds16(A + (size_t)(mBase + amp) * 1024 + k0 + 32 + aql * 8, &Al[nxt][(wave * 64) * 8]);
#pragma unroll
      for (int i = 0; i < 2; i++) {
        const int c = i * 256 + t;
        const int mp = c >> 2, ql = (c & 3) ^ ((mp >> 1) & 3);
        gload_lds16(Bt + (size_t)(nBase + mp) * 1024 + k0 + 32 + ql * 8,
                    &Bl[nxt][(i * 256 + wave * 64) * 8]);
      }
    }
    bf16x8 a[2], bfr[4];
#pragma unroll
    for (int i = 0; i < 2; i++) a[i] = load8(&Al[cur][((wm + i * 16 + ln) * 4 + bswz) * 8]);
#pragma unroll
    for (int jj = 0; jj < 4; jj++) bfr[jj] = load8(&Bl[cur][((wn + jj * 16 + ln) * 4 + bswz) * 8]);
#pragma unroll
    for (int i = 0; i < 2; i++)
#pragma unroll
      for (int jj = 0; jj < 4; jj++) acc[i][jj] = MFMA16(a[i], bfr[jj], acc[i][jj]);
    __syncthreads();
  }

#pragma unroll
  for (int i = 0; i < 2; i++)
#pragma unroll
    for (int jj = 0; jj < 4; jj++)
#pragma unroll
      for (int r = 0; r < 4; r++)
        outp[(size_t)(mBase + wm + i * 16 + quad * 4 + r) * 1024 + nBase + wn + jj * 16 + ln] =
            acc[i][jj][r];
}

extern "C" void kernel_launch(void* const* d_in, const int* in_sizes, int n_in,
                              void* d_out, int out_size, void* d_ws, size_t ws_size,
                              hipStream_t stream) {
  (void)in_sizes; (void)n_in; (void)out_size; (void)ws_size;
  const float* Q  = (const float*)d_in[0];
  const float* K  = (const float*)d_in[1];
  const float* V  = (const float*)d_in[2];
  const float* WQ = (const float*)d_in[3];
  const float* WK = (const float*)d_in[4];
  const float* WV = (const float*)d_in[5];
  const float* WO = (const float*)d_in[6];
  float* outp = (float*)d_out;

  const size_t REG = (size_t)4 * 1024 * 1024;  // 4M bf16 elems = 8MB per region
  bf16* base = (bf16*)d_ws;
  bf16* Wt   = base;            // 3M elems, dead after proj
  bf16* cc   = base;            // [4096][1024], written by attn
  bf16* qws  = base + REG;      // dead after attn
  bf16* WOt  = base + REG;      // 1M elems, written after attn
  bf16* kws  = base + 2 * REG;
  bf16* vtws = base + 3 * REG;

  wcvt_kernel<<<dim3(2, 32, 48), 256, 0, stream>>>(WQ, WK, WV, Wt);
  proj_kernel<<<dim3(768), 256, 0, stream>>>(Q, K, V, Wt, qws, kws, vtws);
  attn_kernel<<<dim3(512), 256, 0, stream>>>(qws, kws, vtws, cc);
  tcvt_kernel<<<dim3(32, 32, 1), 256, 0, stream>>>(WO, WOt, 1024, 1024);
  out_kernel<<<dim3(8 * 64), 256, 0, stream>>>(cc, WOt, outp);
}

// Round 6
// 235.366 us; speedup vs baseline: 1.0340x; 1.0340x over previous
//
#include <hip/hip_runtime.h>
#include <hip/hip_bf16.h>

// MHA: H=16, DM=1024, DK=DV=64, S=2048, B=2. fp32 in/out, bf16 MFMA internals.
// ws (32MB): [0,8MB): Wt (3x2MB, dead after proj) -> reused as cc [4096][1024] bf16
//            [8,16MB): qws [hb][s][64] -> reused as WOt [n][k] after attn
//            [16,24MB): kws [hb][s][64]
//            [24,32MB): vtws [hb][d][pos] (transposed V, pos permuted per 64-block)

typedef __bf16 bf16;
typedef bf16 bf16x8 __attribute__((ext_vector_type(8)));
typedef bf16 bf16x4 __attribute__((ext_vector_type(4)));
typedef float f32x4 __attribute__((ext_vector_type(4)));

#define MFMA16(a, b, c) __builtin_amdgcn_mfma_f32_16x16x32_bf16((a), (b), (c), 0, 0, 0)

static __device__ __forceinline__ bf16x8 load8(const bf16* p) {
  return *reinterpret_cast<const bf16x8*>(p);
}
static __device__ __forceinline__ void store8(bf16* p, bf16x8 v) {
  *reinterpret_cast<bf16x8*>(p) = v;
}
static __device__ __forceinline__ void store4(bf16* p, bf16x4 v) {
  *reinterpret_cast<bf16x4*>(p) = v;
}
static __device__ __forceinline__ bf16x8 cvt8(float4 a, float4 b) {
  bf16x8 o;
  o[0] = (bf16)a.x; o[1] = (bf16)a.y; o[2] = (bf16)a.z; o[3] = (bf16)a.w;
  o[4] = (bf16)b.x; o[5] = (bf16)b.y; o[6] = (bf16)b.z; o[7] = (bf16)b.w;
  return o;
}
static __device__ __forceinline__ f32x4 zero4() {
  f32x4 v; v[0] = 0.f; v[1] = 0.f; v[2] = 0.f; v[3] = 0.f; return v;
}
// async global->LDS, 16B per lane; lds base wave-uniform (HW scatters lane*16)
static __device__ __forceinline__ void gload_lds16(const void* g, void* l) {
  __builtin_amdgcn_global_load_lds(
      (const __attribute__((address_space(1))) void*)g,
      (__attribute__((address_space(3))) void*)l, 16, 0, 0);
}

// ---------------------------------------------------------------------------
// K0a: merged W transpose+convert. z: 0..47 -> (tensor=z/16, head=z%16).
// in[h][1024][64] -> Wt[z*64 + d][m].  WQ scaled by 0.125*log2(e) (exp2 softmax).
// ---------------------------------------------------------------------------
__global__ __launch_bounds__(256) void wcvt_kernel(const float* __restrict__ WQ,
                                                   const float* __restrict__ WK,
                                                   const float* __restrict__ WV,
                                                   bf16* __restrict__ out) {
  __shared__ float tile[32][33];
  const int zz = blockIdx.z;
  const int tau = zz >> 4;
  const float* in = ((tau == 0) ? WQ : (tau == 1) ? WK : WV) + (size_t)(zz & 15) * 65536;
  bf16* o = out + (size_t)zz * 65536;
  const float scale = (tau == 0) ? 0.125f * 1.44269504f : 1.0f;
  const int r0 = blockIdx.y * 32, c0 = blockIdx.x * 32;
  const int tx = threadIdx.x & 31, ty = threadIdx.x >> 5;
#pragma unroll
  for (int i = 0; i < 32; i += 8) tile[ty + i][tx] = in[(size_t)(r0 + ty + i) * 64 + c0 + tx];
  __syncthreads();
#pragma unroll
  for (int i = 0; i < 32; i += 8)
    o[(size_t)(c0 + ty + i) * 1024 + r0 + tx] = (bf16)(tile[tx][ty + i] * scale);
}

// ---------------------------------------------------------------------------
// K0b: generic transpose+convert (for WO 1024x1024).
// ---------------------------------------------------------------------------
__global__ __launch_bounds__(256) void tcvt_kernel(const float* __restrict__ in,
                                                   bf16* __restrict__ out, int R, int C) {
  __shared__ float tile[32][33];
  const int r0 = blockIdx.y * 32, c0 = blockIdx.x * 32;
  const int tx = threadIdx.x & 31, ty = threadIdx.x >> 5;
#pragma unroll
  for (int i = 0; i < 32; i += 8) tile[ty + i][tx] = in[(size_t)(r0 + ty + i) * C + c0 + tx];
  __syncthreads();
#pragma unroll
  for (int i = 0; i < 32; i += 8)
    out[(size_t)(c0 + ty + i) * R + r0 + tx] = (bf16)tile[tx][ty + i];
}

// ---------------------------------------------------------------------------
// K1: QKV projection.  Both operands staged ASYNC (global_load_lds):
//   A: raw fp32 chunks, xor-swizzled; fp32->bf16 cvt happens AFTER ds_read,
//      co-issued with MFMA (VALU and MFMA pipes overlap, m114) — removes the
//      R5 critical chain (global->VGPR->cvt->ds_write->barrier).
//   B: bf16 chunks, xor-swizzled (unchanged).
// LDS dbuf, 1 barrier/step.  Linear grid 768: id = n*96 + w (w=z*32+m) so the
// 8 n-blocks sharing an X panel have the same id%8 -> same XCD -> X L2-shared.
// ---------------------------------------------------------------------------
__global__ __launch_bounds__(256) void proj_kernel(
    const float* __restrict__ X0, const float* __restrict__ X1, const float* __restrict__ X2,
    const bf16* __restrict__ Wt, bf16* __restrict__ qws, bf16* __restrict__ kws,
    bf16* __restrict__ vtws) {
  const int id = blockIdx.x;
  const int n = id / 96;
  const int w = id % 96;
  const int z = w >> 5;
  const int m = w & 31;
  const float* X = (z == 0) ? X0 : ((z == 1) ? X1 : X2);
  const bf16* Wz = Wt + (size_t)z * 1024 * 1024;
  const int mBase = m * 128;
  const int nBase = n * 128;

  __shared__ float Afl[2][128 * 32];  // fp32 tile, swizzled 16B chunks (2x16KB)
  __shared__ bf16 Bl[2][128 * 32];    // bf16 tile, swizzled (2x8KB)

  const int t = threadIdx.x;
  const int lane = t & 63;
  const int wave = t >> 6;
  const int wm = (wave >> 1) * 64;
  const int wn = (wave & 1) * 64;
  const int ln = lane & 15;
  const int quad = lane >> 4;
  const int bswz = quad ^ ((ln >> 1) & 3);

  f32x4 acc[4][4];
#pragma unroll
  for (int i = 0; i < 4; i++)
#pragma unroll
    for (int j = 0; j < 4; j++) acc[i][j] = zero4();

  // A tile: 128 rows x 8 fp32-chunks (16B=4 floats). chunk c -> row c>>3,
  // logical chunk c&7 stored at physical (c&7)^(row&7).
  // B tile: 128 rows x 4 bf16-chunks, physical (c&3)^((row>>1)&3).
  auto issueA = [&](int k0, float* dst) {
#pragma unroll
    for (int i = 0; i < 4; i++) {
      const int c = i * 256 + t;
      const int mp = c >> 3;
      const int ql = (c & 7) ^ (mp & 7);
      gload_lds16(X + (size_t)(mBase + mp) * 1024 + k0 + ql * 4,
                  dst + (i * 256 + wave * 64) * 4);
    }
  };
  auto issueB = [&](int k0, bf16* dst) {
#pragma unroll
    for (int i = 0; i < 2; i++) {
      const int c = i * 256 + t;
      const int mp = c >> 2;
      const int ql = (c & 3) ^ ((mp >> 1) & 3);
      gload_lds16(Wz + (size_t)(nBase + mp) * 1024 + k0 + ql * 8,
                  dst + (i * 256 + wave * 64) * 8);
    }
  };

  issueB(0, Bl[0]);
  issueA(0, Afl[0]);
  __syncthreads();

  for (int k0 = 0; k0 < 1024; k0 += 32) {
    const int cur = (k0 >> 5) & 1, nxt = cur ^ 1;
    const bool more = (k0 + 32) < 1024;
    if (more) {
      issueB(k0 + 32, Bl[nxt]);
      issueA(k0 + 32, Afl[nxt]);
    }
    bf16x8 a[4], bfr[4];
#pragma unroll
    for (int i = 0; i < 4; i++) {
      const int mrow = wm + i * 16 + ln;
      const float4 f0 = *reinterpret_cast<const float4*>(
          &Afl[cur][(mrow * 8 + ((2 * quad) ^ (mrow & 7))) * 4]);
      const float4 f1 = *reinterpret_cast<const float4*>(
          &Afl[cur][(mrow * 8 + ((2 * quad + 1) ^ (mrow & 7))) * 4]);
      a[i] = cvt8(f0, f1);
    }
#pragma unroll
    for (int j = 0; j < 4; j++) bfr[j] = load8(&Bl[cur][((wn + j * 16 + ln) * 4 + bswz) * 8]);
#pragma unroll
    for (int i = 0; i < 4; i++)
#pragma unroll
      for (int j = 0; j < 4; j++) acc[i][j] = MFMA16(a[i], bfr[j], acc[i][j]);
    __syncthreads();
  }

  // Epilogue: C/D row=quad*4+r, col=ln
#pragma unroll
  for (int i = 0; i < 4; i++) {
#pragma unroll
    for (int j = 0; j < 4; j++) {
      const int col = nBase + wn + j * 16 + ln;
      const int h = col >> 6, d = col & 63;
#pragma unroll
      for (int r = 0; r < 4; r++) {
        const int row = mBase + wm + i * 16 + quad * 4 + r;  // row = s*2+b
        const int s = row >> 1, bb = row & 1;
        const int hb = h * 2 + bb;
        const bf16 val = (bf16)acc[i][j][r];
        if (z == 0) {
          qws[((size_t)hb * 2048 + s) * 64 + d] = val;
        } else if (z == 1) {
          kws[((size_t)hb * 2048 + s) * 64 + d] = val;
        } else {
          // 64-granular permuted pos: kv=s&63 -> p = (kv&15)*4 + (kv>>4)
          const int pos = (s & ~63) | ((s & 15) << 2) | ((s >> 4) & 3);
          vtws[((size_t)hb * 64 + d) * 2048 + pos] = val;
        }
      }
    }
  }
}

// ---------------------------------------------------------------------------
// K2: causal flash attention.  Grid 512 = hb(32) x qb(16), descending work
// (qb = 15 - id>>5 -> 32-tile blocks dispatch first).  Block = 128 q-rows,
// 4 waves x 32 rows, KV tile 64.
//   K: LDS double-buffer, async global_load_lds, 1 barrier/tile.
//   V: B-frags straight from global (L2-resident, wave-invariant -> no LDS).
//   P: per-wave padded LDS (stride 72 -> all accesses <=2-way, free).
// LDS total 34KB.  Softmax in exp2 domain (log2e folded into WQ).
// ---------------------------------------------------------------------------
__global__ __launch_bounds__(256, 3) void attn_kernel(
    const bf16* __restrict__ qws, const bf16* __restrict__ kws, const bf16* __restrict__ vtws,
    bf16* __restrict__ cc) {
  const int id = blockIdx.x;
  const int hb = id & 31;          // same hb -> same XCD (id%8 preserved)
  const int qb = 15 - (id >> 5);   // big blocks first
  const int q0 = qb * 128;
  const int h = hb >> 1, b = hb & 1;

  const int t = threadIdx.x;
  const int lane = t & 63;
  const int wave = t >> 6;
  const int ln = lane & 15;
  const int quad = lane >> 4;
  const int swz3 = ln & 7;

  const bf16* qh = qws + (size_t)hb * 2048 * 64;
  const bf16* kh = kws + (size_t)hb * 2048 * 64;
  const bf16* vh = vtws + (size_t)hb * 64 * 2048;

  __shared__ bf16 Kl[2][64 * 64];  // swizzled [kv][64], dbuf (16KB)
  __shared__ bf16 Pl[4][32 * 72];  // per-wave P, padded stride 72 (18KB)
  bf16* Plw = &Pl[wave][0];

  bf16x8 ones;
#pragma unroll
  for (int i = 0; i < 8; i++) ones[i] = (bf16)1.0f;

  // Q A-frags: rows q0+wave*32+mb*16+ln, k = hh*32+quad*8+j
  bf16x8 qf[2][2];
#pragma unroll
  for (int mb = 0; mb < 2; mb++)
#pragma unroll
    for (int hh = 0; hh < 2; hh++)
      qf[mb][hh] = load8(qh + (size_t)(q0 + wave * 32 + mb * 16 + ln) * 64 + hh * 32 + quad * 8);

  f32x4 accO[2][4];
  f32x4 accL[2];
#pragma unroll
  for (int mb = 0; mb < 2; mb++) {
    accL[mb] = zero4();
#pragma unroll
    for (int d = 0; d < 4; d++) accO[mb][d] = zero4();
  }

  // prologue: stage K tile 0 (64 rows x 64 = 512 16B chunks, xor-swizzled)
#pragma unroll
  for (int i = 0; i < 2; i++) {
    const int c = i * 256 + t;
    const int mp = c >> 3;
    const int ql = (c & 7) ^ (mp & 7);
    gload_lds16(kh + (size_t)mp * 64 + ql * 8, &Kl[0][(i * 256 + wave * 64) * 8]);
  }

  const int Jmax = 2 * qb + 2;
  for (int jt = 0; jt < Jmax; jt++) {
    const int kt0 = jt * 64;
    const int cur = jt & 1, nxt = cur ^ 1;
    __syncthreads();  // drains tile-jt async loads (issued a full tile ago)
    if (jt + 1 < Jmax) {
      const int nt0 = kt0 + 64;
#pragma unroll
      for (int i = 0; i < 2; i++) {
        const int c = i * 256 + t;
        const int mp = c >> 3;
        const int ql = (c & 7) ^ (mp & 7);
        gload_lds16(kh + (size_t)(nt0 + mp) * 64 + ql * 8, &Kl[nxt][(i * 256 + wave * 64) * 8]);
      }
    }

    // S = Q K^T  (log2e*scale folded into Q)
    f32x4 sv[2][4];
#pragma unroll
    for (int nt = 0; nt < 4; nt++) {
      const int mm = nt * 16 + ln;
      bf16x8 b0 = load8(&Kl[cur][(mm * 8 + (quad ^ swz3)) * 8]);
      bf16x8 b1 = load8(&Kl[cur][(mm * 8 + ((quad + 4) ^ swz3)) * 8]);
#pragma unroll
      for (int mb = 0; mb < 2; mb++) {
        f32x4 s = MFMA16(qf[mb][0], b0, zero4());
        s = MFMA16(qf[mb][1], b1, s);
        sv[mb][nt] = s;
      }
    }

    // V B-frags from global (L2): row d*16+ln, 16B at pos kt0+(ks*4+quad)*8
    bf16x8 vb[2][4];
#pragma unroll
    for (int ks = 0; ks < 2; ks++)
#pragma unroll
      for (int d = 0; d < 4; d++)
        vb[ks][d] = load8(vh + (size_t)(d * 16 + ln) * 2048 + kt0 + (ks * 4 + quad) * 8);

    if (jt >= 2 * qb) {  // diagonal tiles: causal mask
#pragma unroll
      for (int mb = 0; mb < 2; mb++)
#pragma unroll
        for (int nt = 0; nt < 4; nt++) {
          const int kg = kt0 + nt * 16 + ln;
#pragma unroll
          for (int r = 0; r < 4; r++) {
            const int qg = q0 + wave * 32 + mb * 16 + quad * 4 + r;
            if (kg > qg) sv[mb][nt][r] = -1e30f;
          }
        }
    }

    // P = 2^S -> per-wave padded LDS, p = ln*4+nt (b64 stores, slot=ln)
#pragma unroll
    for (int mb = 0; mb < 2; mb++) {
#pragma unroll
      for (int r = 0; r < 4; r++) {
        const int row = mb * 16 + quad * 4 + r;
        bf16x4 pw;
#pragma unroll
        for (int nt = 0; nt < 4; nt++) pw[nt] = (bf16)exp2f(sv[mb][nt][r]);
        store4(Plw + row * 72 + ln * 4, pw);
      }
    }

    // O += P V ; l += P * 1   (same-wave DS in-order: no barrier needed)
#pragma unroll
    for (int ks = 0; ks < 2; ks++) {
      bf16x8 pa[2];
#pragma unroll
      for (int mb = 0; mb < 2; mb++)
        pa[mb] = load8(Plw + (mb * 16 + ln) * 72 + (ks * 4 + quad) * 8);
#pragma unroll
      for (int d = 0; d < 4; d++)
#pragma unroll
        for (int mb = 0; mb < 2; mb++) accO[mb][d] = MFMA16(pa[mb], vb[ks][d], accO[mb][d]);
#pragma unroll
      for (int mb = 0; mb < 2; mb++) accL[mb] = MFMA16(pa[mb], ones, accL[mb]);
    }
  }

  // epilogue: O /= l, write concat [s*2+b][h*64+...]
#pragma unroll
  for (int mb = 0; mb < 2; mb++) {
#pragma unroll
    for (int r = 0; r < 4; r++) {
      const float inv = 1.0f / accL[mb][r];
      const int s = q0 + wave * 32 + mb * 16 + quad * 4 + r;
#pragma unroll
      for (int d = 0; d < 4; d++)
        cc[((size_t)s * 2 + b) * 1024 + h * 64 + d * 16 + ln] = (bf16)(accO[mb][d][r] * inv);
    }
  }
}

// ---------------------------------------------------------------------------
// K3: output projection, dbuf async both operands. Grid 512: id = n*64+m so
// the 8 n-blocks sharing a cc panel share an XCD. Tile 64m x 128n.
// ---------------------------------------------------------------------------
__global__ __launch_bounds__(256) void out_kernel(
    const bf16* __restrict__ A, const bf16* __restrict__ Bt, float* __restrict__ outp) {
  const int id = blockIdx.x;
  const int nb = id >> 6;
  const int mb = id & 63;
  const int mBase = mb * 64, nBase = nb * 128;

  __shared__ bf16 Al[2][64 * 32];
  __shared__ bf16 Bl[2][128 * 32];

  const int t = threadIdx.x;
  const int lane = t & 63;
  const int wave = t >> 6;
  const int wm = (wave >> 1) * 32;
  const int wn = (wave & 1) * 64;
  const int ln = lane & 15;
  const int quad = lane >> 4;
  const int bswz = quad ^ ((ln >> 1) & 3);

  f32x4 acc[2][4];
#pragma unroll
  for (int i = 0; i < 2; i++)
#pragma unroll
    for (int j = 0; j < 4; j++) acc[i][j] = zero4();

  const int amp = t >> 2, aql = (t & 3) ^ ((amp >> 1) & 3);

  // prologue: tile 0
  gload_lds16(A + (size_t)(mBase + amp) * 1024 + aql * 8, &Al[0][(wave * 64) * 8]);
#pragma unroll
  for (int i = 0; i < 2; i++) {
    const int c = i * 256 + t;
    const int mp = c >> 2, ql = (c & 3) ^ ((mp >> 1) & 3);
    gload_lds16(Bt + (size_t)(nBase + mp) * 1024 + ql * 8, &Bl[0][(i * 256 + wave * 64) * 8]);
  }
  __syncthreads();

  for (int k0 = 0; k0 < 1024; k0 += 32) {
    const int cur = (k0 >> 5) & 1, nxt = cur ^ 1;
    const bool more = (k0 + 32) < 1024;
    if (more) {
      gload_lds16(A + (size_t)(mBase + amp) * 1024 + k0 + 32 + aql * 8, &Al[nxt][(wave * 64) * 8]);
#pragma unroll
      for (int i = 0; i < 2; i++) {
        const int c = i * 256 + t;
        const int mp = c >> 2, ql = (c & 3) ^ ((mp >> 1) & 3);
        gload_lds16(Bt + (size_t)(nBase + mp) * 1024 + k0 + 32 + ql * 8,
                    &Bl[nxt][(i * 256 + wave * 64) * 8]);
      }
    }
    bf16x8 a[2], bfr[4];
#pragma unroll
    for (int i = 0; i < 2; i++) a[i] = load8(&Al[cur][((wm + i * 16 + ln) * 4 + bswz) * 8]);
#pragma unroll
    for (int jj = 0; jj < 4; jj++) bfr[jj] = load8(&Bl[cur][((wn + jj * 16 + ln) * 4 + bswz) * 8]);
#pragma unroll
    for (int i = 0; i < 2; i++)
#pragma unroll
      for (int jj = 0; jj < 4; jj++) acc[i][jj] = MFMA16(a[i], bfr[jj], acc[i][jj]);
    __syncthreads();
  }

#pragma unroll
  for (int i = 0; i < 2; i++)
#pragma unroll
    for (int jj = 0; jj < 4; jj++)
#pragma unroll
      for (int r = 0; r < 4; r++)
        outp[(size_t)(mBase + wm + i * 16 + quad * 4 + r) * 1024 + nBase + wn + jj * 16 + ln] =
            acc[i][jj][r];
}

extern "C" void kernel_launch(void* const* d_in, const int* in_sizes, int n_in,
                              void* d_out, int out_size, void* d_ws, size_t ws_size,
                              hipStream_t stream) {
  (void)in_sizes; (void)n_in; (void)out_size; (void)ws_size;
  const float* Q  = (const float*)d_in[0];
  const float* K  = (const float*)d_in[1];
  const float* V  = (const float*)d_in[2];
  const float* WQ = (const float*)d_in[3];
  const float* WK = (const float*)d_in[4];
  const float* WV = (const float*)d_in[5];
  const float* WO = (const float*)d_in[6];
  float* outp = (float*)d_out;

  const size_t REG = (size_t)4 * 1024 * 1024;  // 4M bf16 elems = 8MB per region
  bf16* base = (bf16*)d_ws;
  bf16* Wt   = base;            // 3M elems, dead after proj
  bf16* cc   = base;            // [4096][1024], written by attn
  bf16* qws  = base + REG;      // dead after attn
  bf16* WOt  = base + REG;      // 1M elems, written after attn
  bf16* kws  = base + 2 * REG;
  bf16* vtws = base + 3 * REG;

  wcvt_kernel<<<dim3(2, 32, 48), 256, 0, stream>>>(WQ, WK, WV, Wt);
  proj_kernel<<<dim3(768), 256, 0, stream>>>(Q, K, V, Wt, qws, kws, vtws);
  attn_kernel<<<dim3(512), 256, 0, stream>>>(qws, kws, vtws, cc);
  tcvt_kernel<<<dim3(32, 32, 1), 256, 0, stream>>>(WO, WOt, 1024, 1024);
  out_kernel<<<dim3(8 * 64), 256, 0, stream>>>(cc, WOt, outp);
}